// Round 2
// baseline (1076.392 us; speedup 1.0000x reference)
//
#include <hip/hip_runtime.h>
#include <hip/hip_bf16.h>

#define NUM_STEPS 10
#define DT 0.1f
#define BK 64

typedef __bf16 bf16_t;
typedef __bf16 bf16x8 __attribute__((ext_vector_type(8)));
typedef __bf16 bf16x4 __attribute__((ext_vector_type(4)));
typedef float f32x4 __attribute__((ext_vector_type(4)));

// async global->LDS, 16B per lane; LDS dst is wave-uniform base + lane*16
__device__ __forceinline__ void async16(const bf16_t* g, bf16_t* l) {
  __builtin_amdgcn_global_load_lds(
      (const __attribute__((address_space(1))) void*)g,
      (__attribute__((address_space(3))) void*)l, 16, 0, 0);
}

__global__ void cvt_f32_to_bf16(const float* __restrict__ in,
                                bf16_t* __restrict__ out, int n4) {
  int i = blockIdx.x * blockDim.x + threadIdx.x;
  if (i < n4) {
    float4 v = ((const float4*)in)[i];
    bf16x4 o = {(bf16_t)v.x, (bf16_t)v.y, (bf16_t)v.z, (bf16_t)v.w};
    ((bf16x4*)out)[i] = o;
  }
}

__global__ void init_h(const float* __restrict__ h0, float* __restrict__ hout,
                       bf16_t* __restrict__ hb, int n4) {
  int i = blockIdx.x * blockDim.x + threadIdx.x;
  if (i < n4) {
    float4 v = ((const float4*)h0)[i];
    ((float4*)hout)[i] = v;
    bf16x4 o = {(bf16_t)v.x, (bf16_t)v.y, (bf16_t)v.z, (bf16_t)v.w};
    ((bf16x4*)hb)[i] = o;
  }
}

// C[M,N] = A[M,K] * B[N,K]^T   (NT, both row-major, K contiguous)
// Pipelined: dbuf LDS, prefetch next K-tile across a raw s_barrier with
// s_waitcnt vmcnt(8) (prefetch loads stay in flight — AITER-style).
// LDS layout: 16-row x 32-col chunks of 1024 B; chunk c = rowGroup*2 + kslice.
// One staging instr writes exactly one chunk (lane -> row=lane&15,
// kcol=(lane>>4)*8); one ds_read_b128 wave-read reads back one chunk
// contiguously -> zero bank conflicts, and it IS the MFMA fragment layout.
template <int EPI>
__global__ __launch_bounds__(256, 2) void gemm_nt(
    const bf16_t* __restrict__ A, const bf16_t* __restrict__ Bw, int M, int N,
    int K, const float* __restrict__ bias1, const float* __restrict__ bias2,
    float* __restrict__ out_ihb, const float* __restrict__ ihb,
    const float* __restrict__ tau, float* __restrict__ h_io,
    bf16_t* __restrict__ hb_next) {
  __shared__ __align__(16) bf16_t As[2][128 * BK];  // 2 x 16 KB
  __shared__ __align__(16) bf16_t Bs[2][128 * BK];  // 2 x 16 KB

  const int tid = threadIdx.x;
  const int lane = tid & 63;
  const int wave = tid >> 6;
  const int waveM = wave >> 1, waveN = wave & 1;

  // XCD-aware swizzle: hardware round-robins linear block id over 8 XCDs.
  // Give each XCD an 8x8 sub-grid: per-XCD L2 in-traffic = 8 A-tiles +
  // 8 B-tiles (~8 MB/step) instead of full-A + 2 B-tiles (17 MB/step).
  const int lin = blockIdx.y * gridDim.x + blockIdx.x;  // 0..511
  const int xcd = lin & 7;
  const int slot = lin >> 3;                            // 0..63
  const int bx = (xcd & 1) * 8 + (slot & 7);            // 0..15
  const int by = (xcd >> 1) * 8 + (slot >> 3);          // 0..31
  const long bRow = (long)by * 128;
  const long bCol = (long)bx * 128;

  // staging lane mapping: row = lane&15 within a 16-row group, col chunk
  // = (lane>>4)*8 within a 32-col k-slice
  const int laneRow = lane & 15;
  const int laneK = (lane >> 4) << 3;
  const bf16_t* aG = A + (bRow + laneRow) * (long)K + laneK;
  const bf16_t* bG = Bw + (bCol + laneRow) * (long)K + laneK;

  // wave w stages rowGroups {2w, 2w+1} x kslices {0,1} for both operands:
  // 8 async16 per wave per K-tile
  auto stage = [&](int p, int k0) {
#pragma unroll
    for (int j = 0; j < 4; ++j) {
      const int rg = wave * 2 + (j >> 1);
      const int ks = j & 1;
      const long go = (long)rg * 16 * K + k0 + ks * 32;
      const int lo = (rg * 2 + ks) * 512;
      async16(aG + go, &As[p][lo]);
      async16(bG + go, &Bs[p][lo]);
    }
  };

  f32x4 acc[4][4] = {};
  const int nIter = K / BK;

  stage(0, 0);
  int p = 0;
  for (int i = 0; i < nIter; ++i) {
    if (i + 1 < nIter) {
      stage(p ^ 1, (i + 1) * BK);
      // wait only for tile i's 8 loads; tile i+1's 8 stay in flight
      asm volatile("s_waitcnt vmcnt(8)" ::: "memory");
    } else {
      asm volatile("s_waitcnt vmcnt(0)" ::: "memory");
    }
    __builtin_amdgcn_s_barrier();  // all waves' tile-i loads landed

    bf16x8 aF[2][4], bF[2][4];
#pragma unroll
    for (int ks = 0; ks < 2; ++ks)
#pragma unroll
      for (int t = 0; t < 4; ++t) {
        aF[ks][t] = *(const bf16x8*)&As[p][((waveM * 4 + t) * 2 + ks) * 512 + lane * 8];
        bF[ks][t] = *(const bf16x8*)&Bs[p][((waveN * 4 + t) * 2 + ks) * 512 + lane * 8];
      }
#pragma unroll
    for (int ks = 0; ks < 2; ++ks)
#pragma unroll
      for (int mt = 0; mt < 4; ++mt)
#pragma unroll
        for (int nt = 0; nt < 4; ++nt)
          acc[mt][nt] = __builtin_amdgcn_mfma_f32_16x16x32_bf16(
              aF[ks][mt], bF[ks][nt], acc[mt][nt], 0, 0, 0);

    // drain own LDS reads, then barrier: after this, buf p may be overwritten
    asm volatile("s_waitcnt lgkmcnt(0)" ::: "memory");
    __builtin_amdgcn_s_barrier();
    p ^= 1;
  }

  // C/D layout: col = lane&15, row = (lane>>4)*4 + reg   [measured m89/m91]
  const int eRow = (lane >> 4) << 2;
  const int eCol = lane & 15;

  if (EPI == 0) {
#pragma unroll
    for (int nt = 0; nt < 4; ++nt) {
      const int col = (int)bCol + waveN * 64 + nt * 16 + eCol;
      const float bb = bias1[col] + bias2[col];
#pragma unroll
      for (int mt = 0; mt < 4; ++mt) {
        const long row = bRow + waveM * 64 + mt * 16 + eRow;
#pragma unroll
        for (int r = 0; r < 4; ++r)
          out_ihb[(row + r) * N + col] = acc[mt][nt][r] + bb;
      }
    }
  } else {
#pragma unroll
    for (int nt = 0; nt < 4; ++nt) {
      const int col = (int)bCol + waveN * 64 + nt * 16 + eCol;
      const float dcy = __expf(-DT / tau[col]);
#pragma unroll
      for (int mt = 0; mt < 4; ++mt) {
        const long row = bRow + waveM * 64 + mt * 16 + eRow;
#pragma unroll
        for (int r = 0; r < 4; ++r) {
          const long idx = (row + r) * N + col;
          float pre = acc[mt][nt][r] + ihb[idx];
          float t = tanhf(pre);
          float hn = dcy * h_io[idx] + (1.0f - dcy) * t;
          h_io[idx] = hn;
          hb_next[idx] = (bf16_t)hn;
        }
      }
    }
  }
}

extern "C" void kernel_launch(void* const* d_in, const int* in_sizes, int n_in,
                              void* d_out, int out_size, void* d_ws,
                              size_t ws_size, hipStream_t stream) {
  const float* x = (const float*)d_in[0];
  const float* h0 = (const float*)d_in[1];
  const float* W_ih = (const float*)d_in[2];
  const float* b_ih = (const float*)d_in[3];
  const float* W_hh = (const float*)d_in[4];
  const float* b_hh = (const float*)d_in[5];
  const float* tau = (const float*)d_in[6];
  float* hout = (float*)d_out;

  const int B = 4096, I = 1024, H = 2048;

  char* ws = (char*)d_ws;
  float* ihb = (float*)ws;   ws += (size_t)B * H * 4;   // 32 MB
  bf16_t* hb0 = (bf16_t*)ws; ws += (size_t)B * H * 2;   // 16 MB
  bf16_t* hb1 = (bf16_t*)ws; ws += (size_t)B * H * 2;   // 16 MB
  bf16_t* xb = (bf16_t*)ws;  ws += (size_t)B * I * 2;   // 8 MB
  bf16_t* wihb = (bf16_t*)ws; ws += (size_t)H * I * 2;  // 4 MB
  bf16_t* whhb = (bf16_t*)ws; ws += (size_t)H * H * 2;  // 8 MB

  cvt_f32_to_bf16<<<(B * I / 4 + 255) / 256, 256, 0, stream>>>(x, xb, B * I / 4);
  cvt_f32_to_bf16<<<(H * I / 4 + 255) / 256, 256, 0, stream>>>(W_ih, wihb, H * I / 4);
  cvt_f32_to_bf16<<<(H * H / 4 + 255) / 256, 256, 0, stream>>>(W_hh, whhb, H * H / 4);
  init_h<<<(B * H / 4 + 255) / 256, 256, 0, stream>>>(h0, hout, hb0, B * H / 4);

  dim3 grid(H / 128, B / 128);  // (16, 32) = 512 blocks
  // ihb = x @ W_ih^T + b_ih + b_hh   (fold both biases once)
  gemm_nt<0><<<grid, 256, 0, stream>>>(xb, wihb, B, H, I, b_ih, b_hh, ihb,
                                       nullptr, nullptr, nullptr, nullptr);

  bf16_t* hb[2] = {hb0, hb1};
  for (int s = 0; s < NUM_STEPS; ++s) {
    gemm_nt<1><<<grid, 256, 0, stream>>>(hb[s & 1], whhb, B, H, H, nullptr,
                                         nullptr, nullptr, ihb, tau, hout,
                                         hb[(s + 1) & 1]);
  }
}

// Round 3
// 980.960 us; speedup vs baseline: 1.0973x; 1.0973x over previous
//
#include <hip/hip_runtime.h>
#include <hip/hip_bf16.h>

#define NUM_STEPS 10
#define DT 0.1f
#define BK 64

typedef __bf16 bf16_t;
typedef __bf16 bf16x8 __attribute__((ext_vector_type(8)));
typedef __bf16 bf16x4 __attribute__((ext_vector_type(4)));
typedef float f32x4 __attribute__((ext_vector_type(4)));

// async global->LDS, 16B per lane; LDS dst is wave-uniform base + lane*16
__device__ __forceinline__ void async16(const bf16_t* g, bf16_t* l) {
  __builtin_amdgcn_global_load_lds(
      (const __attribute__((address_space(1))) void*)g,
      (__attribute__((address_space(3))) void*)l, 16, 0, 0);
}

__global__ void cvt_f32_to_bf16(const float* __restrict__ in,
                                bf16_t* __restrict__ out, int n4) {
  int i = blockIdx.x * blockDim.x + threadIdx.x;
  if (i < n4) {
    float4 v = ((const float4*)in)[i];
    bf16x4 o = {(bf16_t)v.x, (bf16_t)v.y, (bf16_t)v.z, (bf16_t)v.w};
    ((bf16x4*)out)[i] = o;
  }
}

__global__ void init_h(const float* __restrict__ h0, float* __restrict__ hout,
                       bf16_t* __restrict__ hb, int n4) {
  int i = blockIdx.x * blockDim.x + threadIdx.x;
  if (i < n4) {
    float4 v = ((const float4*)h0)[i];
    ((float4*)hout)[i] = v;
    bf16x4 o = {(bf16_t)v.x, (bf16_t)v.y, (bf16_t)v.z, (bf16_t)v.w};
    ((bf16x4*)hb)[i] = o;
  }
}

// C[M,N] = A[M,K] * B[N,K]^T   (NT, both row-major, K contiguous)
// 512 threads (8 waves) per 128x128 tile -> 2 blocks/CU = 16 waves/CU,
// matching m97's concurrency (the round-1/2 bottleneck was 8 waves/CU).
// Plain m97 2-barrier K-loop (manual vmcnt pipelining measured neutral/regressive).
// LDS: 16-row x 32-col chunks of 1 KB; one async16 writes one chunk; one
// ds_read_b128 wave-read reads one chunk back contiguously (0 bank conflicts,
// verified round 2) and it IS the MFMA fragment layout.
// EPI=0: out_ihb(bf16) = acc + bias1[col] + bias2[col]
// EPI=1: pre = acc + ihb; h_io = d*h_io + (1-d)*tanh(pre); hb_next = bf16(h_io)
template <int EPI>
__global__ __launch_bounds__(512, 4) void gemm_nt(
    const bf16_t* __restrict__ A, const bf16_t* __restrict__ Bw, int M, int N,
    int K, const float* __restrict__ bias1, const float* __restrict__ bias2,
    bf16_t* __restrict__ out_ihb, const bf16_t* __restrict__ ihb,
    const float* __restrict__ tau, float* __restrict__ h_io,
    bf16_t* __restrict__ hb_next) {
  __shared__ __align__(16) bf16_t As[128 * BK];  // 16 KB
  __shared__ __align__(16) bf16_t Bs[128 * BK];  // 16 KB

  const int tid = threadIdx.x;
  const int lane = tid & 63;
  const int wave = tid >> 6;     // 0..7
  const int waveM = wave >> 2;   // 0..1  (64-row half)
  const int waveN = wave & 3;    // 0..3  (32-col quarter)

  // XCD swizzle (verified: FETCH 135->97 MB): 8x8 tile sub-grid per XCD
  const int lin = blockIdx.y * gridDim.x + blockIdx.x;  // 0..511
  const int xcd = lin & 7;
  const int slot = lin >> 3;
  const int bx = (xcd & 1) * 8 + (slot & 7);   // 0..15
  const int by = (xcd >> 1) * 8 + (slot >> 3); // 0..31
  const long bRow = (long)by * 128;
  const long bCol = (long)bx * 128;

  // staging: wave w covers rows [w*16, w*16+16) for both operands;
  // lane -> row = lane&15, kcol = (lane>>4)*8 within a 32-col k-slice
  const int laneRow = lane & 15;
  const int laneK = (lane >> 4) << 3;
  const bf16_t* aG = A + (bRow + wave * 16 + laneRow) * (long)K + laneK;
  const bf16_t* bG = Bw + (bCol + wave * 16 + laneRow) * (long)K + laneK;
  bf16_t* aL0 = &As[(wave * 2 + 0) * 512];
  bf16_t* aL1 = &As[(wave * 2 + 1) * 512];
  bf16_t* bL0 = &Bs[(wave * 2 + 0) * 512];
  bf16_t* bL1 = &Bs[(wave * 2 + 1) * 512];

  f32x4 acc[4][2] = {};

  for (int k0 = 0; k0 < K; k0 += BK) {
    async16(aG + k0, aL0);
    async16(aG + k0 + 32, aL1);
    async16(bG + k0, bL0);
    async16(bG + k0 + 32, bL1);
    __syncthreads();  // compiler emits the vmcnt drain before s_barrier

#pragma unroll
    for (int ks = 0; ks < 2; ++ks) {
      bf16x8 aF[4], bF[2];
#pragma unroll
      for (int t = 0; t < 4; ++t)
        aF[t] = *(const bf16x8*)&As[((waveM * 4 + t) * 2 + ks) * 512 + lane * 8];
#pragma unroll
      for (int u = 0; u < 2; ++u)
        bF[u] = *(const bf16x8*)&Bs[((waveN * 2 + u) * 2 + ks) * 512 + lane * 8];
#pragma unroll
      for (int t = 0; t < 4; ++t)
#pragma unroll
        for (int u = 0; u < 2; ++u)
          acc[t][u] = __builtin_amdgcn_mfma_f32_16x16x32_bf16(
              aF[t], bF[u], acc[t][u], 0, 0, 0);
    }
    __syncthreads();
  }

  // C/D layout: col = lane&15, row = (lane>>4)*4 + reg   [measured m89/m91]
  const int eRow = (lane >> 4) << 2;
  const int eCol = lane & 15;

  if (EPI == 0) {
#pragma unroll
    for (int u = 0; u < 2; ++u) {
      const int col = (int)bCol + waveN * 32 + u * 16 + eCol;
      const float bb = bias1[col] + bias2[col];
#pragma unroll
      for (int t = 0; t < 4; ++t) {
        const long row = bRow + waveM * 64 + t * 16 + eRow;
#pragma unroll
        for (int r = 0; r < 4; ++r)
          out_ihb[(row + r) * N + col] = (bf16_t)(acc[t][u][r] + bb);
      }
    }
  } else {
#pragma unroll
    for (int u = 0; u < 2; ++u) {
      const int col = (int)bCol + waveN * 32 + u * 16 + eCol;
      const float dcy = __expf(-DT / tau[col]);
#pragma unroll
      for (int t = 0; t < 4; ++t) {
        const long row = bRow + waveM * 64 + t * 16 + eRow;
#pragma unroll
        for (int r = 0; r < 4; ++r) {
          const long idx = (row + r) * N + col;
          float pre = acc[t][u][r] + (float)ihb[idx];
          float th = tanhf(pre);
          float hn = dcy * h_io[idx] + (1.0f - dcy) * th;
          h_io[idx] = hn;
          hb_next[idx] = (bf16_t)hn;
        }
      }
    }
  }
}

extern "C" void kernel_launch(void* const* d_in, const int* in_sizes, int n_in,
                              void* d_out, int out_size, void* d_ws,
                              size_t ws_size, hipStream_t stream) {
  const float* x = (const float*)d_in[0];
  const float* h0 = (const float*)d_in[1];
  const float* W_ih = (const float*)d_in[2];
  const float* b_ih = (const float*)d_in[3];
  const float* W_hh = (const float*)d_in[4];
  const float* b_hh = (const float*)d_in[5];
  const float* tau = (const float*)d_in[6];
  float* hout = (float*)d_out;

  const int B = 4096, I = 1024, H = 2048;

  char* ws = (char*)d_ws;
  bf16_t* ihb = (bf16_t*)ws; ws += (size_t)B * H * 2;   // 16 MB
  bf16_t* hb0 = (bf16_t*)ws; ws += (size_t)B * H * 2;   // 16 MB
  bf16_t* hb1 = (bf16_t*)ws; ws += (size_t)B * H * 2;   // 16 MB
  bf16_t* xb = (bf16_t*)ws;  ws += (size_t)B * I * 2;   // 8 MB
  bf16_t* wihb = (bf16_t*)ws; ws += (size_t)H * I * 2;  // 4 MB
  bf16_t* whhb = (bf16_t*)ws; ws += (size_t)H * H * 2;  // 8 MB

  cvt_f32_to_bf16<<<(B * I / 4 + 255) / 256, 256, 0, stream>>>(x, xb, B * I / 4);
  cvt_f32_to_bf16<<<(H * I / 4 + 255) / 256, 256, 0, stream>>>(W_ih, wihb, H * I / 4);
  cvt_f32_to_bf16<<<(H * H / 4 + 255) / 256, 256, 0, stream>>>(W_hh, whhb, H * H / 4);
  init_h<<<(B * H / 4 + 255) / 256, 256, 0, stream>>>(h0, hout, hb0, B * H / 4);

  dim3 grid(H / 128, B / 128);  // (16, 32) = 512 blocks, 2/CU, 16 waves/CU
  // ihb = x @ W_ih^T + b_ih + b_hh   (fold both biases once, store bf16)
  gemm_nt<0><<<grid, 512, 0, stream>>>(xb, wihb, B, H, I, b_ih, b_hh, ihb,
                                       nullptr, nullptr, nullptr, nullptr);

  bf16_t* hb[2] = {hb0, hb1};
  for (int s = 0; s < NUM_STEPS; ++s) {
    gemm_nt<1><<<grid, 512, 0, stream>>>(hb[s & 1], whhb, B, H, H, nullptr,
                                         nullptr, nullptr, ihb, tau, hout,
                                         hb[(s + 1) & 1]);
  }
}

// Round 4
// 935.765 us; speedup vs baseline: 1.1503x; 1.0483x over previous
//
#include <hip/hip_runtime.h>
#include <hip/hip_bf16.h>

#define NUM_STEPS 10
#define DT 0.1f
#define BK 64

typedef __bf16 bf16_t;
typedef __bf16 bf16x8 __attribute__((ext_vector_type(8)));
typedef __bf16 bf16x4 __attribute__((ext_vector_type(4)));
typedef float f32x4 __attribute__((ext_vector_type(4)));

// async global->LDS, 16B per lane; LDS dst is wave-uniform base + lane*16
__device__ __forceinline__ void async16(const bf16_t* g, bf16_t* l) {
  __builtin_amdgcn_global_load_lds(
      (const __attribute__((address_space(1))) void*)g,
      (__attribute__((address_space(3))) void*)l, 16, 0, 0);
}

__global__ void cvt_f32_to_bf16(const float* __restrict__ in,
                                bf16_t* __restrict__ out, int n4) {
  int i = blockIdx.x * blockDim.x + threadIdx.x;
  if (i < n4) {
    float4 v = ((const float4*)in)[i];
    bf16x4 o = {(bf16_t)v.x, (bf16_t)v.y, (bf16_t)v.z, (bf16_t)v.w};
    ((bf16x4*)out)[i] = o;
  }
}

// C[M,N] = A[M,K] * B[N,K]^T   (NT, both row-major, K contiguous)
// K-loop identical to round 3 (verified, 0 bank conflicts). The change is the
// epilogue: acc is round-tripped through LDS (two 64-row passes, swizzled
// layout) so ALL global I/O is vectorized float4/bf16x4 instead of scattered
// 4B stores in C-fragment order — rounds 1-3 spent ~half the dispatch there.
// EPI=0: ihb(bf16) = acc + bias1[col] + bias2[col]
// EPI=1: pre = acc + ihb; hn = d*hb_prev + (1-d)*tanh(pre); hb_next = bf16(hn);
//        if writeOut: out_f32 = hn   (final step only)
template <int EPI>
__global__ __launch_bounds__(512, 4) void gemm_nt(
    const bf16_t* __restrict__ A, const bf16_t* __restrict__ Bw, int M, int N,
    int K, const float* __restrict__ bias1, const float* __restrict__ bias2,
    bf16_t* __restrict__ out_ihb, const bf16_t* __restrict__ ihb,
    const float* __restrict__ tau, const bf16_t* __restrict__ hb_prev,
    bf16_t* __restrict__ hb_next, float* __restrict__ out_f32, int writeOut) {
  __shared__ __align__(16) char smem[32768];
  bf16_t* As = (bf16_t*)smem;            // 16 KB (K-loop phase)
  bf16_t* Bs = (bf16_t*)(smem + 16384);  // 16 KB (K-loop phase)
  float* Ep = (float*)smem;              // 32 KB (epilogue phase, 64x128 f32)

  const int tid = threadIdx.x;
  const int lane = tid & 63;
  const int wave = tid >> 6;     // 0..7
  const int waveM = wave >> 2;   // 0..1  (64-row half)
  const int waveN = wave & 3;    // 0..3  (32-col quarter)

  // XCD swizzle (verified: FETCH 135->97->82 MB): 8x8 tile sub-grid per XCD
  const int lin = blockIdx.y * gridDim.x + blockIdx.x;  // 0..511
  const int xcd = lin & 7;
  const int slot = lin >> 3;
  const int bx = (xcd & 1) * 8 + (slot & 7);   // 0..15
  const int by = (xcd >> 1) * 8 + (slot >> 3); // 0..31
  const long bRow = (long)by * 128;
  const long bCol = (long)bx * 128;

  // staging: wave w covers rows [w*16, w*16+16); lane -> row = lane&15,
  // kcol = (lane>>4)*8 within a 32-col k-slice (matches frag layout on readback)
  const int laneRow = lane & 15;
  const int laneK = (lane >> 4) << 3;
  const bf16_t* aG = A + (bRow + wave * 16 + laneRow) * (long)K + laneK;
  const bf16_t* bG = Bw + (bCol + wave * 16 + laneRow) * (long)K + laneK;
  bf16_t* aL0 = &As[(wave * 2 + 0) * 512];
  bf16_t* aL1 = &As[(wave * 2 + 1) * 512];
  bf16_t* bL0 = &Bs[(wave * 2 + 0) * 512];
  bf16_t* bL1 = &Bs[(wave * 2 + 1) * 512];

  f32x4 acc[4][2] = {};

  for (int k0 = 0; k0 < K; k0 += BK) {
    async16(aG + k0, aL0);
    async16(aG + k0 + 32, aL1);
    async16(bG + k0, bL0);
    async16(bG + k0 + 32, bL1);
    __syncthreads();  // compiler emits the vmcnt drain before s_barrier

#pragma unroll
    for (int ks = 0; ks < 2; ++ks) {
      bf16x8 aF[4], bF[2];
#pragma unroll
      for (int t = 0; t < 4; ++t)
        aF[t] = *(const bf16x8*)&As[((waveM * 4 + t) * 2 + ks) * 512 + lane * 8];
#pragma unroll
      for (int u = 0; u < 2; ++u)
        bF[u] = *(const bf16x8*)&Bs[((waveN * 2 + u) * 2 + ks) * 512 + lane * 8];
#pragma unroll
      for (int t = 0; t < 4; ++t)
#pragma unroll
        for (int u = 0; u < 2; ++u)
          acc[t][u] = __builtin_amdgcn_mfma_f32_16x16x32_bf16(
              aF[t], bF[u], acc[t][u], 0, 0, 0);
    }
    __syncthreads();
  }

  // ---- epilogue: LDS transpose to row-linear, then coalesced global I/O ----
  // C/D layout: col = lane&15, row = (lane>>4)*4 + reg   [measured m89/m91]
  const int eRow = (lane >> 4) << 2;
  const int eCol = lane & 15;
  // reader mapping: thread -> row r (0..63), 4 float4-groups cg = (tid&7)*4+j
  const int rdRow = tid >> 3;
  const int rdK = tid & 7;

  for (int p = 0; p < 2; ++p) {
    if (p) __syncthreads();  // pass-0 reads done before pass-1 overwrites Ep
    if (waveM == p) {
      // swizzled store: phys = row*128 + ((col + 4*row) & 127)  (2-way max)
#pragma unroll
      for (int u = 0; u < 2; ++u) {
        const int colL = waveN * 32 + u * 16 + eCol;
#pragma unroll
        for (int t = 0; t < 4; ++t) {
#pragma unroll
          for (int r = 0; r < 4; ++r) {
            const int rowL = t * 16 + eRow + r;
            Ep[rowL * 128 + ((colL + 4 * rowL) & 127)] = acc[t][u][r];
          }
        }
      }
    }
    __syncthreads();

    const long grow = bRow + p * 64 + rdRow;
#pragma unroll
    for (int j = 0; j < 4; ++j) {
      const int cg = rdK * 4 + j;  // float4-group 0..31
      const float4 v =
          *(const float4*)&Ep[rdRow * 128 + ((4 * cg + 4 * rdRow) & 127)];
      const long g = grow * N + bCol + 4 * cg;
      if (EPI == 0) {
        const float4 b1 = *(const float4*)&bias1[bCol + 4 * cg];
        const float4 b2 = *(const float4*)&bias2[bCol + 4 * cg];
        bf16x4 o;
        o[0] = (bf16_t)(v.x + b1.x + b2.x);
        o[1] = (bf16_t)(v.y + b1.y + b2.y);
        o[2] = (bf16_t)(v.z + b1.z + b2.z);
        o[3] = (bf16_t)(v.w + b1.w + b2.w);
        *(bf16x4*)&out_ihb[g] = o;
      } else {
        const bf16x4 ih4 = *(const bf16x4*)&ihb[g];
        const bf16x4 hp4 = *(const bf16x4*)&hb_prev[g];
        const float4 tv = *(const float4*)&tau[bCol + 4 * cg];
        float pre[4] = {v.x + (float)ih4[0], v.y + (float)ih4[1],
                        v.z + (float)ih4[2], v.w + (float)ih4[3]};
        float dcy[4] = {__expf(-DT / tv.x), __expf(-DT / tv.y),
                        __expf(-DT / tv.z), __expf(-DT / tv.w)};
        float hn[4];
        bf16x4 o;
#pragma unroll
        for (int e = 0; e < 4; ++e) {
          const float th = tanhf(pre[e]);
          hn[e] = dcy[e] * (float)hp4[e] + (1.0f - dcy[e]) * th;
          o[e] = (bf16_t)hn[e];
        }
        *(bf16x4*)&hb_next[g] = o;
        if (writeOut) {
          float4 ov = {hn[0], hn[1], hn[2], hn[3]};
          *(float4*)&out_f32[g] = ov;
        }
      }
    }
  }
}

extern "C" void kernel_launch(void* const* d_in, const int* in_sizes, int n_in,
                              void* d_out, int out_size, void* d_ws,
                              size_t ws_size, hipStream_t stream) {
  const float* x = (const float*)d_in[0];
  const float* h0 = (const float*)d_in[1];
  const float* W_ih = (const float*)d_in[2];
  const float* b_ih = (const float*)d_in[3];
  const float* W_hh = (const float*)d_in[4];
  const float* b_hh = (const float*)d_in[5];
  const float* tau = (const float*)d_in[6];
  float* hout = (float*)d_out;

  const int B = 4096, I = 1024, H = 2048;

  char* ws = (char*)d_ws;
  bf16_t* ihb = (bf16_t*)ws; ws += (size_t)B * H * 2;   // 16 MB
  bf16_t* hb0 = (bf16_t*)ws; ws += (size_t)B * H * 2;   // 16 MB
  bf16_t* hb1 = (bf16_t*)ws; ws += (size_t)B * H * 2;   // 16 MB
  bf16_t* xb = (bf16_t*)ws;  ws += (size_t)B * I * 2;   // 8 MB
  bf16_t* wihb = (bf16_t*)ws; ws += (size_t)H * I * 2;  // 4 MB
  bf16_t* whhb = (bf16_t*)ws; ws += (size_t)H * H * 2;  // 8 MB

  cvt_f32_to_bf16<<<(B * I / 4 + 255) / 256, 256, 0, stream>>>(x, xb, B * I / 4);
  cvt_f32_to_bf16<<<(H * I / 4 + 255) / 256, 256, 0, stream>>>(W_ih, wihb, H * I / 4);
  cvt_f32_to_bf16<<<(H * H / 4 + 255) / 256, 256, 0, stream>>>(W_hh, whhb, H * H / 4);
  cvt_f32_to_bf16<<<(B * H / 4 + 255) / 256, 256, 0, stream>>>(h0, hb0, B * H / 4);

  dim3 grid(H / 128, B / 128);  // (16, 32) = 512 blocks
  // ihb = x @ W_ih^T + b_ih + b_hh   (fold both biases once, store bf16)
  gemm_nt<0><<<grid, 512, 0, stream>>>(xb, wihb, B, H, I, b_ih, b_hh, ihb,
                                       nullptr, nullptr, nullptr, nullptr,
                                       nullptr, 0);

  bf16_t* hb[2] = {hb0, hb1};
  for (int s = 0; s < NUM_STEPS; ++s) {
    gemm_nt<1><<<grid, 512, 0, stream>>>(
        hb[s & 1], whhb, B, H, H, nullptr, nullptr, nullptr, ihb, tau,
        hb[s & 1], hb[(s + 1) & 1], hout, (s == NUM_STEPS - 1) ? 1 : 0);
  }
}